// Round 1
// baseline (68636.603 us; speedup 1.0000x reference)
//
#include <hip/hip_runtime.h>
#include <hip/hip_bf16.h>

// GRU: B=64, T=2048, D=H=O=1024.
// Persistent-kernel scan: 256 blocks (2 batch-groups x 128 column-blocks),
// weights resident in VGPRs as MFMA B-fragments, global counter sync per step.

#define Bb 64
#define Tt 2048
#define Dd 1024
#define Hh 1024
#define Oo 1024

typedef __attribute__((ext_vector_type(8))) short bf16x8;
typedef __attribute__((ext_vector_type(4))) float f32x4;

__device__ __forceinline__ short f2bf(float x) {
    __hip_bfloat16 h = __float2bfloat16(x);
    return __builtin_bit_cast(short, h);
}

__device__ __forceinline__ bf16x8 pack8(float4 a, float4 b) {
    bf16x8 f;
    f[0] = f2bf(a.x); f[1] = f2bf(a.y); f[2] = f2bf(a.z); f[3] = f2bf(a.w);
    f[4] = f2bf(b.x); f[5] = f2bf(b.y); f[6] = f2bf(b.z); f[7] = f2bf(b.w);
    return f;
}

// ---------------- x -> bf16 pre-conversion (optional, ws-gated) --------------
__global__ void cvt_x_kernel(const float* __restrict__ x,
                             unsigned short* __restrict__ xb, long n) {
    long i = ((long)blockIdx.x * blockDim.x + threadIdx.x) * 8;
    long stride = (long)gridDim.x * blockDim.x * 8;
    for (; i < n; i += stride) {
        float4 a = *(const float4*)(x + i);
        float4 b = *(const float4*)(x + i + 4);
        *(bf16x8*)(xb + i) = pack8(a, b);
    }
}

// ---------------- persistent GRU scan ----------------------------------------
// grid 256 x 256 threads. block: g = bid&1 (batch group of 32), c = bid>>1
// (owns H-columns [c*8, c*8+8) => weight rows {r,u,n} x 8 = 24 rows of 3H).
// wave w in 0..3 owns K-range [w*512, w*512+512): w<2 -> x-part, w>=2 -> h-part.
template <bool USE_XB>
__global__ __launch_bounds__(256, 1)
void gru_scan(const float* __restrict__ x, const unsigned short* __restrict__ xb,
              const float* __restrict__ Wx, const float* __restrict__ bx,
              const float* __restrict__ Wh, const float* __restrict__ bh,
              unsigned short* __restrict__ hbuf, float* __restrict__ hfinal,
              unsigned int* sync_cnt, unsigned int* sync_go) {
    const int tid = threadIdx.x;
    const int w   = tid >> 6;
    const int l   = tid & 63;
    const int bid = blockIdx.x;
    const int g   = bid & 1;
    const int c   = bid >> 1;
    const int bg0 = g * 32;
    const int j0  = c * 8;

    __shared__ float comb[4][32][24];  // [wave][batch-local][weight-row]
    __shared__ float hp[32][8];        // private fp32 copy of own h columns
    __shared__ float bxv[24], bhv[24];

    // init private h state + biases
    hp[tid >> 3][tid & 7] = 0.0f;
    if (tid < 24) {
        const int gate = tid >> 3, jj = tid & 7;
        bxv[tid] = bx[gate * 1024 + j0 + jj];
        bhv[tid] = bh[gate * 1024 + j0 + jj];
    }

    // ---- load weight B-fragments into registers (held for the whole scan) ----
    const int lm = l & 15;   // tile row/col within 16
    const int lk = l >> 4;   // k-subgroup 0..3
    const int wb = w * 512;  // wave k-base
    bf16x8 bfr[2][16];
    {
        const float* Wbase = (w < 2) ? Wx : Wh;
        const int krel = (w < 2) ? wb : (wb - 1024);
#pragma unroll
        for (int nt = 0; nt < 2; ++nt) {
            int row24 = nt * 16 + lm;
            if (row24 > 23) row24 = 23;  // junk lanes clamped (outputs discarded)
            const int gate = row24 >> 3, jj = row24 & 7;
            const float* rp = Wbase + (size_t)(gate * 1024 + j0 + jj) * 1024 + krel + lk * 8;
#pragma unroll
            for (int ks = 0; ks < 16; ++ks) {
                float4 a = *(const float4*)(rp + ks * 32);
                float4 b = *(const float4*)(rp + ks * 32 + 4);
                bfr[nt][ks] = pack8(a, b);
            }
        }
    }
    __syncthreads();

#pragma unroll 1
    for (int t = 0; t < Tt; ++t) {
        if (t > 0) {
            if (tid == 0) {
                while (__hip_atomic_load(sync_go, __ATOMIC_RELAXED,
                                         __HIP_MEMORY_SCOPE_AGENT) < (unsigned)t) {}
            }
            __syncthreads();
            __builtin_amdgcn_fence(__ATOMIC_ACQUIRE, "agent");  // invalidate stale L2 (cross-XCD h)
        }
        const unsigned short* hcur = hbuf + (size_t)(t & 1) * Bb * Hh;

        f32x4 acc[2][2] = {};  // [m-tile][n-tile]
        if (w < 2) {
            // x-part of K
#pragma unroll
            for (int ks = 0; ks < 16; ++ks) {
#pragma unroll
                for (int mt = 0; mt < 2; ++mt) {
                    const size_t row = (size_t)(bg0 + mt * 16 + lm);
                    const size_t off = (row * Tt + t) * Dd + wb + ks * 32 + lk * 8;
                    bf16x8 af;
                    if (USE_XB) {
                        af = *(const bf16x8*)(xb + off);
                    } else {
                        float4 a = *(const float4*)(x + off);
                        float4 b = *(const float4*)(x + off + 4);
                        af = pack8(a, b);
                    }
                    acc[mt][0] = __builtin_amdgcn_mfma_f32_16x16x32_bf16(af, bfr[0][ks], acc[mt][0], 0, 0, 0);
                    acc[mt][1] = __builtin_amdgcn_mfma_f32_16x16x32_bf16(af, bfr[1][ks], acc[mt][1], 0, 0, 0);
                }
            }
        } else {
            // h-part of K
#pragma unroll
            for (int ks = 0; ks < 16; ++ks) {
#pragma unroll
                for (int mt = 0; mt < 2; ++mt) {
                    const size_t row = (size_t)(bg0 + mt * 16 + lm);
                    bf16x8 af = *(const bf16x8*)(hcur + row * Hh + (wb - 1024) + ks * 32 + lk * 8);
                    acc[mt][0] = __builtin_amdgcn_mfma_f32_16x16x32_bf16(af, bfr[0][ks], acc[mt][0], 0, 0, 0);
                    acc[mt][1] = __builtin_amdgcn_mfma_f32_16x16x32_bf16(af, bfr[1][ks], acc[mt][1], 0, 0, 0);
                }
            }
        }

        // write K-partials for cross-wave reduce. C/D: col=lane&15, row=(lane>>4)*4+i
#pragma unroll
        for (int mt = 0; mt < 2; ++mt)
#pragma unroll
            for (int nt = 0; nt < 2; ++nt) {
                const int n = nt * 16 + lm;
                if (n < 24) {
#pragma unroll
                    for (int i = 0; i < 4; ++i)
                        comb[w][mt * 16 + lk * 4 + i][n] = acc[mt][nt][i];
                }
            }
        __syncthreads();

        // gate phase: thread = (batch-local b, col j)
        {
            const int b = tid >> 3, j = tid & 7;
            const float rz = comb[0][b][j] + comb[1][b][j] + comb[2][b][j] + comb[3][b][j]
                             + bxv[j] + bhv[j];
            const float uz = comb[0][b][8 + j] + comb[1][b][8 + j] + comb[2][b][8 + j]
                             + comb[3][b][8 + j] + bxv[8 + j] + bhv[8 + j];
            const float nx = comb[0][b][16 + j] + comb[1][b][16 + j] + bxv[16 + j];
            const float nh = comb[2][b][16 + j] + comb[3][b][16 + j] + bhv[16 + j];
            const float r  = 1.0f / (1.0f + __expf(-rz));
            const float u  = 1.0f / (1.0f + __expf(-uz));
            const float zz = nx + r * nh;
            const float e2 = __expf(2.0f * zz);
            const float nv = 1.0f - 2.0f / (e2 + 1.0f);  // tanh, overflow-safe
            const float hold = hp[b][j];
            const float hy = u * hold + (1.0f - u) * nv;
            hp[b][j] = hy;
            unsigned short* hnxt = hbuf + (size_t)((t + 1) & 1) * Bb * Hh;
            hnxt[(size_t)(bg0 + b) * Hh + j0 + j] = (unsigned short)f2bf(hy);
            if (t == Tt - 1) hfinal[(size_t)(bg0 + b) * Hh + j0 + j] = hy;
        }
        __syncthreads();  // drains all waves' h stores (vmcnt 0 before barrier)
        __builtin_amdgcn_fence(__ATOMIC_RELEASE, "agent");  // wbl2: h visible in L3
        if (tid == 0) {
            unsigned int old = __hip_atomic_fetch_add(sync_cnt, 1u, __ATOMIC_RELAXED,
                                                      __HIP_MEMORY_SCOPE_AGENT);
            if (old == (unsigned)(256 * (t + 1) - 1))
                __hip_atomic_store(sync_go, (unsigned)(t + 1), __ATOMIC_RELEASE,
                                   __HIP_MEMORY_SCOPE_AGENT);
        }
    }
}

// ---------------- final projection + log_softmax ------------------------------
__global__ __launch_bounds__(1024)
void final_kernel(const float* __restrict__ hfinal, const float* __restrict__ Wf,
                  const float* __restrict__ bfv, float* __restrict__ out) {
    const int b = blockIdx.x;
    const int o = threadIdx.x;
    __shared__ float hs[1024];
    __shared__ float redm[16], redsum[16], bcast[2];
    hs[o] = hfinal[(size_t)b * 1024 + o];
    __syncthreads();

    const float* wr = Wf + (size_t)o * 1024;
    float acc = bfv[o];
#pragma unroll 4
    for (int k = 0; k < 1024; k += 4) {
        float4 wv = *(const float4*)(wr + k);
        acc += hs[k] * wv.x + hs[k + 1] * wv.y + hs[k + 2] * wv.z + hs[k + 3] * wv.w;
    }

    float m = acc;
#pragma unroll
    for (int off = 32; off > 0; off >>= 1) m = fmaxf(m, __shfl_xor(m, off));
    if ((o & 63) == 0) redm[o >> 6] = m;
    __syncthreads();
    if (o == 0) {
        float mm = redm[0];
#pragma unroll
        for (int i = 1; i < 16; ++i) mm = fmaxf(mm, redm[i]);
        bcast[0] = mm;
    }
    __syncthreads();
    const float bm = bcast[0];
    float s = __expf(acc - bm);
#pragma unroll
    for (int off = 32; off > 0; off >>= 1) s += __shfl_xor(s, off);
    if ((o & 63) == 0) redsum[o >> 6] = s;
    __syncthreads();
    if (o == 0) {
        float ss = 0.0f;
        for (int i = 0; i < 16; ++i) ss += redsum[i];
        bcast[1] = logf(ss);
    }
    __syncthreads();
    out[(size_t)b * 1024 + o] = acc - bm - bcast[1];
}

// ---------------- launch ------------------------------------------------------
extern "C" void kernel_launch(void* const* d_in, const int* in_sizes, int n_in,
                              void* d_out, int out_size, void* d_ws, size_t ws_size,
                              hipStream_t stream) {
    (void)in_sizes; (void)n_in; (void)out_size;
    const float* x   = (const float*)d_in[0];
    const float* Wx  = (const float*)d_in[1];
    const float* bx  = (const float*)d_in[2];
    const float* Wh  = (const float*)d_in[3];
    const float* bh  = (const float*)d_in[4];
    const float* Wf  = (const float*)d_in[5];
    const float* bfv = (const float*)d_in[6];
    float* out = (float*)d_out;

    char* ws = (char*)d_ws;
    unsigned int* sync_cnt = (unsigned int*)ws;
    unsigned int* sync_go  = (unsigned int*)(ws + 64);
    unsigned short* hbuf   = (unsigned short*)(ws + 1024);                    // 2*64*1024*2 = 262144 B
    float* hfinal          = (float*)(ws + 1024 + 262144);                    // 262144 B
    unsigned short* xb     = (unsigned short*)(ws + 1024 + 262144 + 262144);
    const size_t base_need = 1024 + 262144 + 262144;
    const size_t xb_need   = (size_t)Bb * Tt * Dd * 2;
    const bool use_xb = (ws_size >= base_need + xb_need);

    // zero sync words + hbuf[0] (h0 = 0); required every launch (no state reuse)
    hipMemsetAsync(d_ws, 0, 1024 + (size_t)Bb * Hh * 2, stream);

    if (use_xb) {
        cvt_x_kernel<<<2048, 256, 0, stream>>>(x, xb, (long)Bb * Tt * Dd);
        gru_scan<true><<<256, 256, 0, stream>>>(x, xb, Wx, bx, Wh, bh,
                                                hbuf, hfinal, sync_cnt, sync_go);
    } else {
        gru_scan<false><<<256, 256, 0, stream>>>(x, xb, Wx, bx, Wh, bh,
                                                 hbuf, hfinal, sync_cnt, sync_go);
    }
    final_kernel<<<64, 1024, 0, stream>>>(hfinal, Wf, bfv, out);
}

// Round 2
// 21640.437 us; speedup vs baseline: 3.1717x; 3.1717x over previous
//
#include <hip/hip_runtime.h>
#include <hip/hip_bf16.h>

// GRU: B=64, T=2048, D=H=O=1024.
// Persistent scan: 256 blocks (2 batch-groups x 128 column-blocks), weights in
// VGPRs as MFMA B-fragments. Cross-block h exchange via device-coherent
// (agent-scope, L2-bypass) atomics + per-group flag sync. NO cache-wide fences.

#define Bb 64
#define Tt 2048
#define Dd 1024
#define Hh 1024

typedef __attribute__((ext_vector_type(8))) short bf16x8;
typedef __attribute__((ext_vector_type(4))) float f32x4;

__device__ __forceinline__ short f2bf(float x) {
    __hip_bfloat16 h = __float2bfloat16(x);
    return __builtin_bit_cast(short, h);
}

__device__ __forceinline__ bf16x8 pack8(float4 a, float4 b) {
    bf16x8 f;
    f[0] = f2bf(a.x); f[1] = f2bf(a.y); f[2] = f2bf(a.z); f[3] = f2bf(a.w);
    f[4] = f2bf(b.x); f[5] = f2bf(b.y); f[6] = f2bf(b.z); f[7] = f2bf(b.w);
    return f;
}

__device__ __forceinline__ unsigned long long ald64(const void* p) {
    return __hip_atomic_load((const unsigned long long*)p, __ATOMIC_RELAXED,
                             __HIP_MEMORY_SCOPE_AGENT);
}
__device__ __forceinline__ unsigned aldu32(const unsigned* p) {
    return __hip_atomic_load(p, __ATOMIC_RELAXED, __HIP_MEMORY_SCOPE_AGENT);
}

// ---------------- persistent GRU scan ----------------------------------------
// block: g = bid&1 (batch group of 32 rows), c = bid>>1 (owns 8 H-columns).
// wave w: K-range [w*512, w*512+512): w<2 -> x-part, w>=2 -> h-part.
template <bool RING>
__global__ __launch_bounds__(256, 1)
void gru_scan(const float* __restrict__ x,
              const float* __restrict__ Wx, const float* __restrict__ bx,
              const float* __restrict__ Wh, const float* __restrict__ bh,
              unsigned short* __restrict__ hbuf, float* __restrict__ hfinal,
              unsigned short* __restrict__ ring, unsigned* __restrict__ flags) {
    const int tid = threadIdx.x;
    const int w   = tid >> 6;
    const int l   = tid & 63;
    const int bid = blockIdx.x;
    const int g   = bid & 1;
    const int c   = bid >> 1;
    const int bg0 = g * 32;
    const int j0  = c * 8;

    __shared__ float comb[4][32][24];
    __shared__ float hp[32][8];
    __shared__ float bxv[24], bhv[24];

    hp[tid >> 3][tid & 7] = 0.0f;
    if (tid < 24) {
        const int gate = tid >> 3, jj = tid & 7;
        bxv[tid] = bx[gate * 1024 + j0 + jj];
        bhv[tid] = bh[gate * 1024 + j0 + jj];
    }

    const int lm = l & 15;
    const int lk = l >> 4;
    const int wb = w * 512;
    // ---- weights resident in registers for the whole scan ----
    bf16x8 bfr[2][16];
    {
        const float* Wbase = (w < 2) ? Wx : Wh;
        const int krel = (w < 2) ? wb : (wb - 1024);
#pragma unroll
        for (int nt = 0; nt < 2; ++nt) {
            int row24 = nt * 16 + lm;
            if (row24 > 23) row24 = 23;
            const int gate = row24 >> 3, jj = row24 & 7;
            const float* rp = Wbase + (size_t)(gate * 1024 + j0 + jj) * 1024 + krel + lk * 8;
#pragma unroll
            for (int ks = 0; ks < 16; ++ks) {
                float4 a = *(const float4*)(rp + ks * 32);
                float4 b = *(const float4*)(rp + ks * 32 + 4);
                bfr[nt][ks] = pack8(a, b);
            }
        }
    }
    __syncthreads();

    // ---- RING prologue: produce bf16 x-slices 0..3, then group barrier ----
    if (RING) {
        if (tid < 128) {
            const int e = c * 256 + tid * 2;
            const int rl = e >> 10, col = e & 1023;
#pragma unroll
            for (int s = 0; s < 4; ++s) {
                const float2 xv = *(const float2*)(x + ((size_t)(bg0 + rl) * Tt + s) * Dd + col);
                unsigned pk = (unsigned)(unsigned short)f2bf(xv.x)
                            | ((unsigned)(unsigned short)f2bf(xv.y) << 16);
                __hip_atomic_store((unsigned*)(ring + (size_t)s * 65536
                                               + (size_t)(bg0 + rl) * 1024 + col),
                                   pk, __ATOMIC_RELAXED, __HIP_MEMORY_SCOPE_AGENT);
            }
        }
        asm volatile("s_waitcnt vmcnt(0)" ::: "memory");
        __syncthreads();
        if (tid == 0)
            __hip_atomic_store(&flags[g * 128 + c], 1u, __ATOMIC_RELAXED,
                               __HIP_MEMORY_SCOPE_AGENT);
        if (tid < 128) {
            const unsigned* f = flags + g * 128 + tid;
            while (aldu32(f) < 1u) __builtin_amdgcn_s_sleep(1);
        }
        asm volatile("" ::: "memory");
        __syncthreads();
    }

#pragma unroll 1
    for (int t = 0; t < Tt; ++t) {
        const unsigned short* hcur = hbuf + (size_t)(t & 1) * Bb * Hh;

        // ---- ring producer: slice t+4, issued early (waves 0-1) ----
        if (RING && tid < 128) {
            const int sp = t + 4;
            if (sp < Tt) {
                const int e = c * 256 + tid * 2;
                const int rl = e >> 10, col = e & 1023;
                const float2 xv = *(const float2*)(x + ((size_t)(bg0 + rl) * Tt + sp) * Dd + col);
                unsigned pk = (unsigned)(unsigned short)f2bf(xv.x)
                            | ((unsigned)(unsigned short)f2bf(xv.y) << 16);
                __hip_atomic_store((unsigned*)(ring + (size_t)(sp & 7) * 65536
                                               + (size_t)(bg0 + rl) * 1024 + col),
                                   pk, __ATOMIC_RELAXED, __HIP_MEMORY_SCOPE_AGENT);
            }
        }

        // ---- h-waves spin for group step-(t-1) completion ----
        if (w >= 2 && t > 0) {
            const unsigned tgt = (unsigned)(t + 1);
            const unsigned* f0 = flags + g * 128 + l;
            const unsigned* f1 = f0 + 64;
            while (aldu32(f0) < tgt || aldu32(f1) < tgt) __builtin_amdgcn_s_sleep(1);
        }
        asm volatile("" ::: "memory");

        f32x4 acc[2][2] = {};
        if (RING || w >= 2) {
            // unified coherent-load path: waves 0-1 read ring slice, 2-3 read h
            const unsigned short* src;
            int colb;
            if (w < 2) { src = ring + (size_t)(t & 7) * 65536; colb = wb; }
            else       { src = hcur;                           colb = wb - 1024; }
#pragma unroll
            for (int half = 0; half < 2; ++half) {
                unsigned long long stg[8][2][2];
#pragma unroll
                for (int k8 = 0; k8 < 8; ++k8) {
                    const int ks = half * 8 + k8;
#pragma unroll
                    for (int mt = 0; mt < 2; ++mt) {
                        const unsigned short* p = src + (size_t)(bg0 + mt * 16 + lm) * 1024
                                                  + colb + ks * 32 + lk * 8;
                        stg[k8][mt][0] = ald64(p);
                        stg[k8][mt][1] = ald64(p + 4);
                    }
                }
#pragma unroll
                for (int k8 = 0; k8 < 8; ++k8) {
                    const int ks = half * 8 + k8;
#pragma unroll
                    for (int mt = 0; mt < 2; ++mt) {
                        struct { unsigned long long a, b; } u{stg[k8][mt][0], stg[k8][mt][1]};
                        bf16x8 af = __builtin_bit_cast(bf16x8, u);
                        acc[mt][0] = __builtin_amdgcn_mfma_f32_16x16x32_bf16(af, bfr[0][ks], acc[mt][0], 0, 0, 0);
                        acc[mt][1] = __builtin_amdgcn_mfma_f32_16x16x32_bf16(af, bfr[1][ks], acc[mt][1], 0, 0, 0);
                    }
                }
            }
        } else {
            // fallback: waves 0-1 read x fp32 directly (plain cached loads)
#pragma unroll
            for (int ks = 0; ks < 16; ++ks) {
#pragma unroll
                for (int mt = 0; mt < 2; ++mt) {
                    const size_t row = (size_t)(bg0 + mt * 16 + lm);
                    const size_t off = (row * Tt + t) * Dd + wb + ks * 32 + lk * 8;
                    float4 a = *(const float4*)(x + off);
                    float4 b = *(const float4*)(x + off + 4);
                    bf16x8 af = pack8(a, b);
                    acc[mt][0] = __builtin_amdgcn_mfma_f32_16x16x32_bf16(af, bfr[0][ks], acc[mt][0], 0, 0, 0);
                    acc[mt][1] = __builtin_amdgcn_mfma_f32_16x16x32_bf16(af, bfr[1][ks], acc[mt][1], 0, 0, 0);
                }
            }
        }

        // K-partials -> LDS. C/D: col=lane&15, row=(lane>>4)*4+i
#pragma unroll
        for (int mt = 0; mt < 2; ++mt)
#pragma unroll
            for (int nt = 0; nt < 2; ++nt) {
                const int n = nt * 16 + lm;
                if (n < 24) {
#pragma unroll
                    for (int i = 0; i < 4; ++i)
                        comb[w][mt * 16 + lk * 4 + i][n] = acc[mt][nt][i];
                }
            }
        __syncthreads();

        // gate phase
        {
            const int b = tid >> 3, j = tid & 7;
            const float rz = comb[0][b][j] + comb[1][b][j] + comb[2][b][j] + comb[3][b][j]
                             + bxv[j] + bhv[j];
            const float uz = comb[0][b][8 + j] + comb[1][b][8 + j] + comb[2][b][8 + j]
                             + comb[3][b][8 + j] + bxv[8 + j] + bhv[8 + j];
            const float nx = comb[0][b][16 + j] + comb[1][b][16 + j] + bxv[16 + j];
            const float nh = comb[2][b][16 + j] + comb[3][b][16 + j] + bhv[16 + j];
            const float r  = 1.0f / (1.0f + __expf(-rz));
            const float u  = 1.0f / (1.0f + __expf(-uz));
            const float zz = nx + r * nh;
            const float e2 = __expf(2.0f * zz);
            const float nv = 1.0f - 2.0f / (e2 + 1.0f);
            const float hold = hp[b][j];
            const float hy = u * hold + (1.0f - u) * nv;
            hp[b][j] = hy;
            unsigned short* hn = hbuf + (size_t)((t + 1) & 1) * Bb * Hh
                                 + (size_t)(bg0 + b) * 1024 + j0 + j;
            __hip_atomic_store(hn, (unsigned short)f2bf(hy), __ATOMIC_RELAXED,
                               __HIP_MEMORY_SCOPE_AGENT);
            if (t == Tt - 1) hfinal[(size_t)(bg0 + b) * 1024 + j0 + j] = hy;
        }
        // all coherent stores (h + ring) acked at L3, then signal
        asm volatile("s_waitcnt vmcnt(0)" ::: "memory");
        __syncthreads();
        if (tid == 0 && t + 1 < Tt)
            __hip_atomic_store(&flags[g * 128 + c], (unsigned)(t + 2), __ATOMIC_RELAXED,
                               __HIP_MEMORY_SCOPE_AGENT);
    }
}

// ---------------- final projection + log_softmax ------------------------------
__global__ __launch_bounds__(1024)
void final_kernel(const float* __restrict__ hfinal, const float* __restrict__ Wf,
                  const float* __restrict__ bfv, float* __restrict__ out) {
    const int b = blockIdx.x;
    const int o = threadIdx.x;
    __shared__ float hs[1024];
    __shared__ float redm[16], redsum[16], bcast[2];
    hs[o] = hfinal[(size_t)b * 1024 + o];
    __syncthreads();

    const float* wr = Wf + (size_t)o * 1024;
    float acc = bfv[o];
#pragma unroll 4
    for (int k = 0; k < 1024; k += 4) {
        float4 wv = *(const float4*)(wr + k);
        acc += hs[k] * wv.x + hs[k + 1] * wv.y + hs[k + 2] * wv.z + hs[k + 3] * wv.w;
    }

    float m = acc;
#pragma unroll
    for (int off = 32; off > 0; off >>= 1) m = fmaxf(m, __shfl_xor(m, off));
    if ((o & 63) == 0) redm[o >> 6] = m;
    __syncthreads();
    if (o == 0) {
        float mm = redm[0];
#pragma unroll
        for (int i = 1; i < 16; ++i) mm = fmaxf(mm, redm[i]);
        bcast[0] = mm;
    }
    __syncthreads();
    const float bm = bcast[0];
    float s = __expf(acc - bm);
#pragma unroll
    for (int off = 32; off > 0; off >>= 1) s += __shfl_xor(s, off);
    if ((o & 63) == 0) redsum[o >> 6] = s;
    __syncthreads();
    if (o == 0) {
        float ss = 0.0f;
        for (int i = 0; i < 16; ++i) ss += redsum[i];
        bcast[1] = logf(ss);
    }
    __syncthreads();
    out[(size_t)b * 1024 + o] = acc - bm - bcast[1];
}

// ---------------- launch ------------------------------------------------------
extern "C" void kernel_launch(void* const* d_in, const int* in_sizes, int n_in,
                              void* d_out, int out_size, void* d_ws, size_t ws_size,
                              hipStream_t stream) {
    (void)in_sizes; (void)n_in; (void)out_size;
    const float* x   = (const float*)d_in[0];
    const float* Wx  = (const float*)d_in[1];
    const float* bx  = (const float*)d_in[2];
    const float* Wh  = (const float*)d_in[3];
    const float* bh  = (const float*)d_in[4];
    const float* Wf  = (const float*)d_in[5];
    const float* bfv = (const float*)d_in[6];
    float* out = (float*)d_out;

    char* ws = (char*)d_ws;
    unsigned* flags        = (unsigned*)ws;                                  // 1 KB
    unsigned short* hbuf   = (unsigned short*)(ws + 1024);                   // 256 KB
    float* hfinal          = (float*)(ws + 1024 + 262144);                   // 256 KB
    unsigned short* ring   = (unsigned short*)(ws + 1024 + 262144 + 262144); // 1 MB
    const size_t need_ring = 1024 + 262144 + 262144 + (size_t)8 * 131072;
    const bool use_ring = (ws_size >= need_ring);

    // zero flags + h0 every launch (deterministic across graph replays)
    hipMemsetAsync(d_ws, 0, 1024 + (size_t)Bb * Hh * 2, stream);

    if (use_ring)
        gru_scan<true><<<256, 256, 0, stream>>>(x, Wx, bx, Wh, bh, hbuf, hfinal, ring, flags);
    else
        gru_scan<false><<<256, 256, 0, stream>>>(x, Wx, bx, Wh, bh, hbuf, hfinal, ring, flags);
    final_kernel<<<64, 1024, 0, stream>>>(hfinal, Wf, bfv, out);
}

// Round 3
// 15458.191 us; speedup vs baseline: 4.4401x; 1.3999x over previous
//
#include <hip/hip_runtime.h>
#include <hip/hip_bf16.h>

// GRU: B=64, T=2048, D=H=O=1024.
// Path A (ws >= ~20MB): xp = x@Wx^T precomputed (bf16, windowed GEMM), then
//   h-only persistent scan: 64 blocks x 512 thr, h-weights in VGPR, coherent
//   h exchange + per-block flags. Fallback: round-2 ring kernel.

#define Bb 64
#define Tt 2048
#define Dd 1024
#define Hh 1024

typedef __attribute__((ext_vector_type(8))) short bf16x8;
typedef __attribute__((ext_vector_type(4))) float f32x4;

__device__ __forceinline__ short f2bf(float x) {
    __hip_bfloat16 h = __float2bfloat16(x);
    return __builtin_bit_cast(short, h);
}
__device__ __forceinline__ float bf2f(unsigned short u) {
    return __builtin_bit_cast(float, (unsigned)u << 16);
}
__device__ __forceinline__ bf16x8 pack8(float4 a, float4 b) {
    bf16x8 f;
    f[0] = f2bf(a.x); f[1] = f2bf(a.y); f[2] = f2bf(a.z); f[3] = f2bf(a.w);
    f[4] = f2bf(b.x); f[5] = f2bf(b.y); f[6] = f2bf(b.z); f[7] = f2bf(b.w);
    return f;
}
__device__ __forceinline__ unsigned long long ald64(const void* p) {
    return __hip_atomic_load((const unsigned long long*)p, __ATOMIC_RELAXED,
                             __HIP_MEMORY_SCOPE_AGENT);
}
__device__ __forceinline__ unsigned aldu32(const unsigned* p) {
    return __hip_atomic_load(p, __ATOMIC_RELAXED, __HIP_MEMORY_SCOPE_AGENT);
}

// ---------------- fp32 -> bf16 convert (weights) ------------------------------
__global__ void wcvt(const float* __restrict__ a, unsigned short* __restrict__ o, long n) {
    long i = ((long)blockIdx.x * blockDim.x + threadIdx.x) * 8;
    long stride = (long)gridDim.x * blockDim.x * 8;
    for (; i < n; i += stride)
        *(bf16x8*)(o + i) = pack8(*(const float4*)(a + i), *(const float4*)(a + i + 4));
}

// ---------------- xp GEMM: xp[t][b][3072] = x[b][t][:] @ Wxb^T ----------------
// grid (24, Wc): block = (n128-tile, slice). 256 thr, 4 waves; wave owns 32 n.
__global__ __launch_bounds__(256)
void xp_gemm(const float* __restrict__ x, const unsigned short* __restrict__ Wxb,
             unsigned short* __restrict__ xp, int t0) {
    __shared__ unsigned short As[64][40];  // padded: 80B rows -> ~2-way banks
    const int tid = threadIdx.x;
    const int wave = tid >> 6, l = tid & 63, lm = l & 15, lk = l >> 4;
    const int slot = blockIdx.y;
    const int t = t0 + slot;
    const int n0w = blockIdx.x * 128 + wave * 32;

    f32x4 acc[4][2] = {};
#pragma unroll 1
    for (int k0 = 0; k0 < 1024; k0 += 32) {
        __syncthreads();
        {
            const int r = tid >> 2, kq = (tid & 3) * 8;
            const float* p = x + (size_t)r * Tt * Dd + (size_t)t * Dd + k0 + kq;
            *(bf16x8*)&As[r][kq] = pack8(*(const float4*)p, *(const float4*)(p + 4));
        }
        __syncthreads();
        bf16x8 bfr[2];
#pragma unroll
        for (int nt = 0; nt < 2; ++nt)
            bfr[nt] = *(const bf16x8*)(Wxb + (size_t)(n0w + nt * 16 + lm) * 1024 + k0 + lk * 8);
#pragma unroll
        for (int mt = 0; mt < 4; ++mt) {
            const bf16x8 af = *(const bf16x8*)&As[mt * 16 + lm][lk * 8];
            acc[mt][0] = __builtin_amdgcn_mfma_f32_16x16x32_bf16(af, bfr[0], acc[mt][0], 0, 0, 0);
            acc[mt][1] = __builtin_amdgcn_mfma_f32_16x16x32_bf16(af, bfr[1], acc[mt][1], 0, 0, 0);
        }
    }
    // D[a_row = lk*4+i (+16*mt)][b_row = lm (+16*nt)]  (empirically verified in scan)
#pragma unroll
    for (int mt = 0; mt < 4; ++mt)
#pragma unroll
        for (int nt = 0; nt < 2; ++nt)
#pragma unroll
            for (int i = 0; i < 4; ++i) {
                const int b = mt * 16 + lk * 4 + i;
                const int n = n0w + nt * 16 + lm;
                xp[((size_t)slot * 64 + b) * 3072 + n] = (unsigned short)f2bf(acc[mt][nt][i]);
            }
}

// ---------------- h-only persistent scan (chunked) ----------------------------
// 64 blocks x 512 thr. block: g = bid&1 (32 batch rows), c = bid>>1 (32 h-cols).
// wave w in 0..7 owns K-range [w*128, w*128+128) of H.
__global__ __launch_bounds__(512, 2)
void gru_scan2(const float* __restrict__ Wh, const float* __restrict__ bx,
               const float* __restrict__ bh, unsigned short* __restrict__ hbuf,
               float* __restrict__ hstate, float* __restrict__ hfinal,
               const unsigned short* __restrict__ xp, unsigned* __restrict__ flags,
               int t0, int tend) {
    const int tid = threadIdx.x;
    const int w = tid >> 6, l = tid & 63, lm = l & 15, lk = l >> 4;
    const int bid = blockIdx.x, g = bid & 1, c = bid >> 1;
    const int bg0 = g * 32, j0 = c * 32;
    const int kb = w * 128;

    __shared__ float comb[8][32][100];   // padded stride 100 -> 2-way banks
    __shared__ float hp[32][32];
    __shared__ float bxv[96], bhv[96];

    if (tid < 96) {
        const int g3 = tid >> 5, jj = tid & 31;
        bxv[tid] = bx[g3 * 1024 + j0 + jj];
        bhv[tid] = bh[g3 * 1024 + j0 + jj];
    }
    const int bgate = tid >> 4, jp = (tid & 15) * 2;
    {
        const float2 h2 = *(const float2*)(hstate + (size_t)(bg0 + bgate) * 1024 + j0 + jp);
        hp[bgate][jp] = h2.x; hp[bgate][jp + 1] = h2.y;
    }

    // ---- h-weight fragments resident in VGPRs ----
    bf16x8 wf[6][4];
#pragma unroll
    for (int nt = 0; nt < 6; ++nt) {
        const int n96 = nt * 16 + lm, g3 = n96 >> 5, jj = n96 & 31;
        const float* rp = Wh + (size_t)(g3 * 1024 + j0 + jj) * 1024 + kb + lk * 8;
#pragma unroll
        for (int ks = 0; ks < 4; ++ks)
            wf[nt][ks] = pack8(*(const float4*)(rp + ks * 32), *(const float4*)(rp + ks * 32 + 4));
    }
    __syncthreads();

#pragma unroll 1
    for (int t = t0; t < tend; ++t) {
        // xp prefetch (plain cached loads; ready since gemm kernel boundary)
        const unsigned short* xrow = xp + ((size_t)(t - t0) * 64 + bg0 + bgate) * 3072 + j0 + jp;
        const unsigned xq0 = *(const unsigned*)(xrow);
        const unsigned xq1 = *(const unsigned*)(xrow + 1024);
        const unsigned xq2 = *(const unsigned*)(xrow + 2048);

        if (t > 0) {
            const unsigned tgt = (unsigned)(t + 1);
            while (!__all((int)(l >= 32 || aldu32(&flags[g * 32 + (l & 31)]) >= tgt)))
                __builtin_amdgcn_s_sleep(2);
        }
        asm volatile("" ::: "memory");

        const unsigned short* hcur = hbuf + (size_t)(t & 1) * Bb * Hh;
        unsigned long long st[2][4][2];
#pragma unroll
        for (int mt = 0; mt < 2; ++mt)
#pragma unroll
            for (int ks = 0; ks < 4; ++ks) {
                const unsigned short* p = hcur + (size_t)(bg0 + mt * 16 + lm) * 1024
                                          + kb + ks * 32 + lk * 8;
                st[mt][ks][0] = ald64(p);
                st[mt][ks][1] = ald64(p + 4);
            }
        f32x4 acc[2][6] = {};
#pragma unroll
        for (int ks = 0; ks < 4; ++ks)
#pragma unroll
            for (int mt = 0; mt < 2; ++mt) {
                struct { unsigned long long a, b; } u{st[mt][ks][0], st[mt][ks][1]};
                const bf16x8 af = __builtin_bit_cast(bf16x8, u);
#pragma unroll
                for (int nt = 0; nt < 6; ++nt)
                    acc[mt][nt] = __builtin_amdgcn_mfma_f32_16x16x32_bf16(af, wf[nt][ks], acc[mt][nt], 0, 0, 0);
            }
#pragma unroll
        for (int mt = 0; mt < 2; ++mt)
#pragma unroll
            for (int nt = 0; nt < 6; ++nt)
#pragma unroll
                for (int i = 0; i < 4; ++i)
                    comb[w][mt * 16 + lk * 4 + i][nt * 16 + lm] = acc[mt][nt][i];
        __syncthreads();

        // ---- gate: thread = (batch b, col pair jp,jp+1) ----
        float hy0, hy1;
        {
            float s00 = 0, s10 = 0, s20 = 0, s01 = 0, s11 = 0, s21 = 0;
#pragma unroll
            for (int ww = 0; ww < 8; ++ww) {
                s00 += comb[ww][bgate][jp];      s01 += comb[ww][bgate][jp + 1];
                s10 += comb[ww][bgate][32 + jp]; s11 += comb[ww][bgate][32 + jp + 1];
                s20 += comb[ww][bgate][64 + jp]; s21 += comb[ww][bgate][64 + jp + 1];
            }
            const float xr0 = bf2f((unsigned short)xq0) + bxv[jp];
            const float xr1 = bf2f((unsigned short)(xq0 >> 16)) + bxv[jp + 1];
            const float xu0 = bf2f((unsigned short)xq1) + bxv[32 + jp];
            const float xu1 = bf2f((unsigned short)(xq1 >> 16)) + bxv[32 + jp + 1];
            const float xn0 = bf2f((unsigned short)xq2) + bxv[64 + jp];
            const float xn1 = bf2f((unsigned short)(xq2 >> 16)) + bxv[64 + jp + 1];
            const float r0 = 1.0f / (1.0f + __expf(-(xr0 + s00 + bhv[jp])));
            const float r1 = 1.0f / (1.0f + __expf(-(xr1 + s01 + bhv[jp + 1])));
            const float u0 = 1.0f / (1.0f + __expf(-(xu0 + s10 + bhv[32 + jp])));
            const float u1 = 1.0f / (1.0f + __expf(-(xu1 + s11 + bhv[32 + jp + 1])));
            const float z0 = xn0 + r0 * (s20 + bhv[64 + jp]);
            const float z1 = xn1 + r1 * (s21 + bhv[64 + jp + 1]);
            const float e0 = __expf(2.0f * z0), e1 = __expf(2.0f * z1);
            const float n0 = 1.0f - 2.0f / (e0 + 1.0f);
            const float n1 = 1.0f - 2.0f / (e1 + 1.0f);
            hy0 = u0 * hp[bgate][jp] + (1.0f - u0) * n0;
            hy1 = u1 * hp[bgate][jp + 1] + (1.0f - u1) * n1;
            hp[bgate][jp] = hy0; hp[bgate][jp + 1] = hy1;
            const unsigned pk = (unsigned)(unsigned short)f2bf(hy0)
                              | ((unsigned)(unsigned short)f2bf(hy1) << 16);
            unsigned short* hn = hbuf + (size_t)((t + 1) & 1) * Bb * Hh
                                 + (size_t)(bg0 + bgate) * 1024 + j0 + jp;
            __hip_atomic_store((unsigned*)hn, pk, __ATOMIC_RELAXED, __HIP_MEMORY_SCOPE_AGENT);
            if (t == tend - 1)
                *(float2*)(hstate + (size_t)(bg0 + bgate) * 1024 + j0 + jp) = make_float2(hy0, hy1);
            if (t == Tt - 1)
                *(float2*)(hfinal + (size_t)(bg0 + bgate) * 1024 + j0 + jp) = make_float2(hy0, hy1);
        }
        asm volatile("s_waitcnt vmcnt(0)" ::: "memory");
        __syncthreads();
        if (tid == 0)
            __hip_atomic_store(&flags[g * 32 + c], (unsigned)(t + 2), __ATOMIC_RELAXED,
                               __HIP_MEMORY_SCOPE_AGENT);
    }
}

// ---------------- round-2 fallback scan (ring) --------------------------------
template <bool RING>
__global__ __launch_bounds__(256, 1)
void gru_scan(const float* __restrict__ x,
              const float* __restrict__ Wx, const float* __restrict__ bx,
              const float* __restrict__ Wh, const float* __restrict__ bh,
              unsigned short* __restrict__ hbuf, float* __restrict__ hfinal,
              unsigned short* __restrict__ ring, unsigned* __restrict__ flags) {
    const int tid = threadIdx.x;
    const int w   = tid >> 6;
    const int l   = tid & 63;
    const int bid = blockIdx.x;
    const int g   = bid & 1;
    const int c   = bid >> 1;
    const int bg0 = g * 32;
    const int j0  = c * 8;

    __shared__ float comb[4][32][24];
    __shared__ float hp[32][8];
    __shared__ float bxv[24], bhv[24];

    hp[tid >> 3][tid & 7] = 0.0f;
    if (tid < 24) {
        const int gate = tid >> 3, jj = tid & 7;
        bxv[tid] = bx[gate * 1024 + j0 + jj];
        bhv[tid] = bh[gate * 1024 + j0 + jj];
    }

    const int lm = l & 15;
    const int lk = l >> 4;
    const int wb = w * 512;
    bf16x8 bfr[2][16];
    {
        const float* Wbase = (w < 2) ? Wx : Wh;
        const int krel = (w < 2) ? wb : (wb - 1024);
#pragma unroll
        for (int nt = 0; nt < 2; ++nt) {
            int row24 = nt * 16 + lm;
            if (row24 > 23) row24 = 23;
            const int gate = row24 >> 3, jj = row24 & 7;
            const float* rp = Wbase + (size_t)(gate * 1024 + j0 + jj) * 1024 + krel + lk * 8;
#pragma unroll
            for (int ks = 0; ks < 16; ++ks) {
                float4 a = *(const float4*)(rp + ks * 32);
                float4 b = *(const float4*)(rp + ks * 32 + 4);
                bfr[nt][ks] = pack8(a, b);
            }
        }
    }
    __syncthreads();

    if (RING) {
        if (tid < 128) {
            const int e = c * 256 + tid * 2;
            const int rl = e >> 10, col = e & 1023;
#pragma unroll
            for (int s = 0; s < 4; ++s) {
                const float2 xv = *(const float2*)(x + ((size_t)(bg0 + rl) * Tt + s) * Dd + col);
                unsigned pk = (unsigned)(unsigned short)f2bf(xv.x)
                            | ((unsigned)(unsigned short)f2bf(xv.y) << 16);
                __hip_atomic_store((unsigned*)(ring + (size_t)s * 65536
                                               + (size_t)(bg0 + rl) * 1024 + col),
                                   pk, __ATOMIC_RELAXED, __HIP_MEMORY_SCOPE_AGENT);
            }
        }
        asm volatile("s_waitcnt vmcnt(0)" ::: "memory");
        __syncthreads();
        if (tid == 0)
            __hip_atomic_store(&flags[g * 128 + c], 1u, __ATOMIC_RELAXED,
                               __HIP_MEMORY_SCOPE_AGENT);
        if (tid < 128) {
            const unsigned* f = flags + g * 128 + tid;
            while (aldu32(f) < 1u) __builtin_amdgcn_s_sleep(1);
        }
        asm volatile("" ::: "memory");
        __syncthreads();
    }

#pragma unroll 1
    for (int t = 0; t < Tt; ++t) {
        const unsigned short* hcur = hbuf + (size_t)(t & 1) * Bb * Hh;

        if (RING && tid < 128) {
            const int sp = t + 4;
            if (sp < Tt) {
                const int e = c * 256 + tid * 2;
                const int rl = e >> 10, col = e & 1023;
                const float2 xv = *(const float2*)(x + ((size_t)(bg0 + rl) * Tt + sp) * Dd + col);
                unsigned pk = (unsigned)(unsigned short)f2bf(xv.x)
                            | ((unsigned)(unsigned short)f2bf(xv.y) << 16);
                __hip_atomic_store((unsigned*)(ring + (size_t)(sp & 7) * 65536
                                               + (size_t)(bg0 + rl) * 1024 + col),
                                   pk, __ATOMIC_RELAXED, __HIP_MEMORY_SCOPE_AGENT);
            }
        }

        if (w >= 2 && t > 0) {
            const unsigned tgt = (unsigned)(t + 1);
            const unsigned* f0 = flags + g * 128 + l;
            const unsigned* f1 = f0 + 64;
            while (aldu32(f0) < tgt || aldu32(f1) < tgt) __builtin_amdgcn_s_sleep(1);
        }
        asm volatile("" ::: "memory");

        f32x4 acc[2][2] = {};
        if (RING || w >= 2) {
            const unsigned short* src;
            int colb;
            if (w < 2) { src = ring + (size_t)(t & 7) * 65536; colb = wb; }
            else       { src = hcur;                           colb = wb - 1024; }
#pragma unroll
            for (int half = 0; half < 2; ++half) {
                unsigned long long stg[8][2][2];
#pragma unroll
                for (int k8 = 0; k8 < 8; ++k8) {
                    const int ks = half * 8 + k8;
#pragma unroll
                    for (int mt = 0; mt < 2; ++mt) {
                        const unsigned short* p = src + (size_t)(bg0 + mt * 16 + lm) * 1024
                                                  + colb + ks * 32 + lk * 8;
                        stg[k8][mt][0] = ald64(p);
                        stg[k8][mt][1] = ald64(p + 4);
                    }
                }
#pragma unroll
                for (int k8 = 0; k8 < 8; ++k8) {
                    const int ks = half * 8 + k8;
#pragma unroll
                    for (int mt = 0; mt < 2; ++mt) {
                        struct { unsigned long long a, b; } u{stg[k8][mt][0], stg[k8][mt][1]};
                        bf16x8 af = __builtin_bit_cast(bf16x8, u);
                        acc[mt][0] = __builtin_amdgcn_mfma_f32_16x16x32_bf16(af, bfr[0][ks], acc[mt][0], 0, 0, 0);
                        acc[mt][1] = __builtin_amdgcn_mfma_f32_16x16x32_bf16(af, bfr[1][ks], acc[mt][1], 0, 0, 0);
                    }
                }
            }
        } else {
#pragma unroll
            for (int ks = 0; ks < 16; ++ks) {
#pragma unroll
                for (int mt = 0; mt < 2; ++mt) {
                    const size_t row = (size_t)(bg0 + mt * 16 + lm);
                    const size_t off = (row * Tt + t) * Dd + wb + ks * 32 + lk * 8;
                    float4 a = *(const float4*)(x + off);
                    float4 b = *(const float4*)(x + off + 4);
                    bf16x8 af = pack8(a, b);
                    acc[mt][0] = __builtin_amdgcn_mfma_f32_16x16x32_bf16(af, bfr[0][ks], acc[mt][0], 0, 0, 0);
                    acc[mt][1] = __builtin_amdgcn_mfma_f32_16x16x32_bf16(af, bfr[1][ks], acc[mt][1], 0, 0, 0);
                }
            }
        }

#pragma unroll
        for (int mt = 0; mt < 2; ++mt)
#pragma unroll
            for (int nt = 0; nt < 2; ++nt) {
                const int n = nt * 16 + lm;
                if (n < 24) {
#pragma unroll
                    for (int i = 0; i < 4; ++i)
                        comb[w][mt * 16 + lk * 4 + i][n] = acc[mt][nt][i];
                }
            }
        __syncthreads();

        {
            const int b = tid >> 3, j = tid & 7;
            const float rz = comb[0][b][j] + comb[1][b][j] + comb[2][b][j] + comb[3][b][j]
                             + bxv[j] + bhv[j];
            const float uz = comb[0][b][8 + j] + comb[1][b][8 + j] + comb[2][b][8 + j]
                             + comb[3][b][8 + j] + bxv[8 + j] + bhv[8 + j];
            const float nx = comb[0][b][16 + j] + comb[1][b][16 + j] + bxv[16 + j];
            const float nh = comb[2][b][16 + j] + comb[3][b][16 + j] + bhv[16 + j];
            const float r  = 1.0f / (1.0f + __expf(-rz));
            const float u  = 1.0f / (1.0f + __expf(-uz));
            const float zz = nx + r * nh;
            const float e2 = __expf(2.0f * zz);
            const float nv = 1.0f - 2.0f / (e2 + 1.0f);
            const float hold = hp[b][j];
            const float hy = u * hold + (1.0f - u) * nv;
            hp[b][j] = hy;
            unsigned short* hn = hbuf + (size_t)((t + 1) & 1) * Bb * Hh
                                 + (size_t)(bg0 + b) * 1024 + j0 + j;
            __hip_atomic_store(hn, (unsigned short)f2bf(hy), __ATOMIC_RELAXED,
                               __HIP_MEMORY_SCOPE_AGENT);
            if (t == Tt - 1) hfinal[(size_t)(bg0 + b) * 1024 + j0 + j] = hy;
        }
        asm volatile("s_waitcnt vmcnt(0)" ::: "memory");
        __syncthreads();
        if (tid == 0 && t + 1 < Tt)
            __hip_atomic_store(&flags[g * 128 + c], (unsigned)(t + 2), __ATOMIC_RELAXED,
                               __HIP_MEMORY_SCOPE_AGENT);
    }
}

// ---------------- final projection + log_softmax ------------------------------
__global__ __launch_bounds__(1024)
void final_kernel(const float* __restrict__ hfinal, const float* __restrict__ Wf,
                  const float* __restrict__ bfv, float* __restrict__ out) {
    const int b = blockIdx.x;
    const int o = threadIdx.x;
    __shared__ float hs[1024];
    __shared__ float redm[16], redsum[16], bcast[2];
    hs[o] = hfinal[(size_t)b * 1024 + o];
    __syncthreads();

    const float* wr = Wf + (size_t)o * 1024;
    float acc = bfv[o];
#pragma unroll 4
    for (int k = 0; k < 1024; k += 4) {
        float4 wv = *(const float4*)(wr + k);
        acc += hs[k] * wv.x + hs[k + 1] * wv.y + hs[k + 2] * wv.z + hs[k + 3] * wv.w;
    }

    float m = acc;
#pragma unroll
    for (int off = 32; off > 0; off >>= 1) m = fmaxf(m, __shfl_xor(m, off));
    if ((o & 63) == 0) redm[o >> 6] = m;
    __syncthreads();
    if (o == 0) {
        float mm = redm[0];
#pragma unroll
        for (int i = 1; i < 16; ++i) mm = fmaxf(mm, redm[i]);
        bcast[0] = mm;
    }
    __syncthreads();
    const float bm = bcast[0];
    float s = __expf(acc - bm);
#pragma unroll
    for (int off = 32; off > 0; off >>= 1) s += __shfl_xor(s, off);
    if ((o & 63) == 0) redsum[o >> 6] = s;
    __syncthreads();
    if (o == 0) {
        float ss = 0.0f;
        for (int i = 0; i < 16; ++i) ss += redsum[i];
        bcast[1] = logf(ss);
    }
    __syncthreads();
    out[(size_t)b * 1024 + o] = acc - bm - bcast[1];
}

// ---------------- launch ------------------------------------------------------
extern "C" void kernel_launch(void* const* d_in, const int* in_sizes, int n_in,
                              void* d_out, int out_size, void* d_ws, size_t ws_size,
                              hipStream_t stream) {
    (void)in_sizes; (void)n_in; (void)out_size;
    const float* x   = (const float*)d_in[0];
    const float* Wx  = (const float*)d_in[1];
    const float* bx  = (const float*)d_in[2];
    const float* Wh  = (const float*)d_in[3];
    const float* bh  = (const float*)d_in[4];
    const float* Wf  = (const float*)d_in[5];
    const float* bfv = (const float*)d_in[6];
    float* out = (float*)d_out;
    char* ws = (char*)d_ws;

    // Path A layout
    const size_t FL = 0;                        // flags, 1 KB
    const size_t HB = 1024;                     // hbuf  (2 x 64x1024 bf16) 256 KB
    const size_t HS = HB + 262144;              // hstate fp32 256 KB
    const size_t HF = HS + 262144;              // hfinal fp32 256 KB
    const size_t WX = HF + 262144;              // Wx bf16 6 MB
    const size_t XP = WX + 6291456;             // xp window: W x 64x3072 bf16
    size_t avail = (ws_size > XP) ? (ws_size - XP) : 0;
    long Wl = (long)(avail / 393216);
    if (Wl > 2048) Wl = 2048;
    const int W = (int)Wl;

    if (W >= 32) {
        unsigned* flags      = (unsigned*)(ws + FL);
        unsigned short* hbuf = (unsigned short*)(ws + HB);
        float* hstate        = (float*)(ws + HS);
        float* hfinal        = (float*)(ws + HF);
        unsigned short* Wxb  = (unsigned short*)(ws + WX);
        unsigned short* xp   = (unsigned short*)(ws + XP);

        hipMemsetAsync(d_ws, 0, HF, stream);  // flags + hbuf + hstate = 0
        wcvt<<<1536, 256, 0, stream>>>(Wx, (unsigned short*)Wxb, 3L * 1024 * 1024);
        for (int t0 = 0; t0 < Tt; t0 += W) {
            const int Wc = (Tt - t0 < W) ? (Tt - t0) : W;
            xp_gemm<<<dim3(24, Wc), 256, 0, stream>>>(x, Wxb, xp, t0);
            gru_scan2<<<64, 512, 0, stream>>>(Wh, bx, bh, hbuf, hstate, hfinal,
                                              xp, flags, t0, t0 + Wc);
        }
        final_kernel<<<64, 1024, 0, stream>>>(hfinal, Wf, bfv, out);
    } else {
        // round-2 fallback layout
        unsigned* flags      = (unsigned*)ws;                                  // 1 KB
        unsigned short* hbuf = (unsigned short*)(ws + 1024);                   // 256 KB
        float* hfinal        = (float*)(ws + 1024 + 262144);                   // 256 KB
        unsigned short* ring = (unsigned short*)(ws + 1024 + 262144 + 262144); // 1 MB
        const size_t need_ring = 1024 + 262144 + 262144 + (size_t)8 * 131072;
        const bool use_ring = (ws_size >= need_ring);

        hipMemsetAsync(d_ws, 0, 1024 + (size_t)Bb * Hh * 2, stream);
        if (use_ring)
            gru_scan<true><<<256, 256, 0, stream>>>(x, Wx, bx, Wh, bh, hbuf, hfinal, ring, flags);
        else
            gru_scan<false><<<256, 256, 0, stream>>>(x, Wx, bx, Wh, bh, hbuf, hfinal, ring, flags);
        final_kernel<<<64, 1024, 0, stream>>>(hfinal, Wf, bfv, out);
    }
}